// Round 14
// baseline (115.595 us; speedup 1.0000x reference)
//
#include <hip/hip_runtime.h>
#include <stdint.h>

#define NPTS   4096
#define NSKIP  16384
#define CCH    256
#define CSK    128
#define DIN    384
#define HDIM   256
#define BIGF   1e10f

typedef unsigned short u16;
typedef __attribute__((ext_vector_type(8))) short short8;
typedef __attribute__((ext_vector_type(4))) float floatx4;

__device__ __forceinline__ u16 f2bf(float f) {
    union { float f; uint32_t u; } c; c.f = f;
    uint32_t u = c.u;
    return (u16)((u + 0x7FFFu + ((u >> 16) & 1u)) >> 16);
}

// Pack (non-negative fp32 dist, idx) into a positive double whose numeric
// order == (dist, idx) lexicographic order (exact top_k tie semantics).
__device__ __forceinline__ double pkkey(float d, int j) {
    return __hiloint2double(__float_as_int(d), j);
}

// ---------------------------------------------------------------------------
// k1 (R20): prep — unchanged from R13. Blocks 0-47 pack W1, 48-79 pack W2
// (ntile-major); blocks 48-63 build pos4; block 0 builds batch range table.
// ---------------------------------------------------------------------------
__global__ __launch_bounds__(256) void prep_kernel(
    const float* __restrict__ W1, const float* __restrict__ W2,
    u16* __restrict__ W1p, u16* __restrict__ W2p,
    const float* __restrict__ pos, float4* __restrict__ pos4,
    const int* __restrict__ batch, int* __restrict__ range)
{
    const int bid = blockIdx.x;
    const int t = threadIdx.x;

    const float* W = (bid < 48) ? W1 : W2;
    u16* Wp       = (bid < 48) ? W1p : W2p;
    const int KT  = (bid < 48) ? 12 : 8;
    const int g   = ((bid < 48) ? bid : (bid - 48)) * 256 + t;

    const int lane = g & 63;
    const int kt = (g >> 6) % KT;
    const int nt = (g >> 6) / KT;
    const int kbase = kt * 32 + (lane >> 4) * 8;
    const int n = nt * 16 + (lane & 15);
    u16 v[8];
#pragma unroll
    for (int j = 0; j < 8; ++j) v[j] = f2bf(W[(size_t)(kbase + j) * HDIM + n]);
#pragma unroll
    for (int j = 0; j < 8; ++j) Wp[(size_t)g * 8 + j] = v[j];

    if (bid >= 48 && bid < 64) {
        const int p = (bid - 48) * 256 + t;
        pos4[p] = make_float4(pos[p * 3 + 0], pos[p * 3 + 1], pos[p * 3 + 2], 0.0f);
    }

    if (bid == 0) {
        for (int j = t * 16; j < t * 16 + 16; ++j) {
            if (j == 0) {
                const int b0 = batch[0];
                for (int b = 0; b <= b0; ++b) range[b] = 0;
            } else {
                const int bp = batch[j - 1], bj = batch[j];
                for (int b = bp + 1; b <= bj; ++b) range[b] = j;
            }
            if (j == NPTS - 1) {
                const int bl = batch[NPTS - 1];
                for (int b = bl + 1; b <= 4; ++b) range[b] = NPTS;
            }
        }
    }
}

// ---------------------------------------------------------------------------
// k2 (R20): mega with wave-specialized half-tile pipeline.
// 32 rows/block, 512 blocks, 1024 threads (16 waves), VGPR<=64.
//  S0: all waves: skip-copy + KNN+gather half0 (1 row/wave, 64 thr/pt)
//  S1: w0-7: GEMM1(half0)        || w8-15: KNN+gather half1 (2 rows, 32 thr)
//  S2: w8-15: GEMM1(half1)       || w0-7:  pack h(half0)
//  S3: w0-7:  GEMM2(half0)       || w8-15: pack h(half1)
//  S4: w8-15: GEMM2(half1)+sOut  || w0-7:  pack sOut(half0)
//  S5: all: coalesced store + tail.
// LDS ranges of concurrent read/write phases are disjoint (audited).
// Selection numerics identical to R13 (same d2 expression, unique keys).
// ---------------------------------------------------------------------------
__global__ __launch_bounds__(1024, 8) void mega_kernel(
    const float* __restrict__ x, const float* __restrict__ x_skip,
    const float4* __restrict__ pos4, const int* __restrict__ range,
    const u16* __restrict__ W1p, const float* __restrict__ b1,
    const u16* __restrict__ W2p, const float* __restrict__ b2,
    const float* __restrict__ pos_skip, const int* __restrict__ batch_skip,
    float* __restrict__ out)
{
    __shared__ u16 sA[32 * 392];     // A bf16 [32][392]; reused as h[32][264]
    __shared__ float sOut[32 * 256]; // f32 epilogue staging
    const int t = threadIdx.x;
    const int row0 = blockIdx.x * 32;
    const int wave = t >> 6, lane = t & 63;
    const int quad = lane >> 4, ml = lane & 15;
    const double BIGKEY = pkkey(BIGF, 0x7FFFFFFF);

    // ---------------- S0 ----------------
    // skip-copy: all 32 rows (32 thr/row)
    {
        const int rl = t >> 5, sub = t & 31;
        const float4 vs = *(const float4*)(x_skip + (size_t)(row0 + rl) * CSK + sub * 4);
        uint2 pk;
        pk.x = (uint32_t)f2bf(vs.x) | ((uint32_t)f2bf(vs.y) << 16);
        pk.y = (uint32_t)f2bf(vs.z) | ((uint32_t)f2bf(vs.w) << 16);
        *(uint2*)(sA + rl * 392 + CCH + sub * 4) = pk;
    }
    // KNN + gather half0: 1 row per wave, 64 threads/pt
    {
        const int rl = wave;                 // 0..15
        const int i = row0 + rl;
        const int b = batch_skip[i];
        const int start = range[b], end = range[b + 1];
        const float px = pos_skip[i * 3 + 0];
        const float py = pos_skip[i * 3 + 1];
        const float pz = pos_skip[i * 3 + 2];

        double k0 = BIGKEY, k1 = BIGKEY, k2 = BIGKEY;
        for (int j = start + lane; j < end; j += 64) {
            const float4 q = pos4[j];
            const float dx = __fsub_rn(px, q.x);
            const float dy = __fsub_rn(py, q.y);
            const float dz = __fsub_rn(pz, q.z);
            const float dd = __fadd_rn(__fadd_rn(__fmul_rn(dx, dx), __fmul_rn(dy, dy)),
                                       __fmul_rn(dz, dz));
            const double kk = pkkey(dd, j);
            const double u0 = fmax(k0, kk); k0 = fmin(k0, kk);
            const double u1 = fmax(k1, u0); k1 = fmin(k1, u0);
            k2 = fmin(k2, u1);
        }
#pragma unroll
        for (int m = 1; m < 64; m <<= 1) {   // 6-step full-wave butterfly
            const double o0 = __shfl_xor(k0, m);
            const double o1 = __shfl_xor(k1, m);
            const double o2 = __shfl_xor(k2, m);
            double u0 = fmax(k0, o0); k0 = fmin(k0, o0);
            double u1 = fmax(k1, u0); k1 = fmin(k1, u0);
            k2 = fmin(k2, u1);
            u1 = fmax(k1, o1); k1 = fmin(k1, o1);
            k2 = fmin(k2, u1);
            k2 = fmin(k2, o2);
        }
        const int i0 = __double2loint(k0);
        const int i1 = __double2loint(k1);
        const int i2 = __double2loint(k2);
        const float d0 = __int_as_float(__double2hiint(k0));
        const float d1 = __int_as_float(__double2hiint(k1));
        const float d2 = __int_as_float(__double2hiint(k2));
        const float w0r = 1.0f / fmaxf(d0, 1e-16f);
        const float w1r = 1.0f / fmaxf(d1, 1e-16f);
        const float w2r = 1.0f / fmaxf(d2, 1e-16f);
        const float inv = 1.0f / (w0r + w1r + w2r);
        const float w0 = w0r * inv, w1 = w1r * inv, w2 = w2r * inv;
        // gather: 4 cols per lane
        const float4 a = *(const float4*)(x + (size_t)i0 * CCH + lane * 4);
        const float4 c = *(const float4*)(x + (size_t)i1 * CCH + lane * 4);
        const float4 e = *(const float4*)(x + (size_t)i2 * CCH + lane * 4);
        const float y0 = w0 * a.x + w1 * c.x + w2 * e.x;
        const float y1 = w0 * a.y + w1 * c.y + w2 * e.y;
        const float y2 = w0 * a.z + w1 * c.z + w2 * e.z;
        const float y3 = w0 * a.w + w1 * c.w + w2 * e.w;
        uint2 pk;
        pk.x = (uint32_t)f2bf(y0) | ((uint32_t)f2bf(y1) << 16);
        pk.y = (uint32_t)f2bf(y2) | ((uint32_t)f2bf(y3) << 16);
        *(uint2*)(sA + rl * 392 + lane * 4) = pk;
    }
    __syncthreads();

    // ---------------- S1 ----------------
    floatx4 acc[2] = {};   // GEMM1 accum (role-dependent half)
    if (wave < 8) {
        // GEMM1 half0: ntiles 2w,2w+1; A rows 0-15
        const u16* aA = sA + ml * 392 + quad * 8;
        for (int kt = 0; kt < 12; ++kt) {
            short8 a0 = *(const short8*)(aA + kt * 32);
#pragma unroll
            for (int nt = 0; nt < 2; ++nt) {
                const int ntile = 2 * wave + nt;
                short8 bfr = *(const short8*)(W1p + (size_t)((ntile * 12 + kt) * 64 + lane) * 8);
                acc[nt] = __builtin_amdgcn_mfma_f32_16x16x32_bf16(a0, bfr, acc[nt], 0, 0, 0);
            }
        }
    } else {
        // KNN + gather half1: 2 rows/wave, 32 thr/pt (R13 path)
        const int rl = 16 + ((wave - 8) << 1) + (lane >> 5);  // 16..31
        const int sub = lane & 31;
        const int i = row0 + rl;
        const int b = batch_skip[i];
        const int start = range[b], end = range[b + 1];
        const float px = pos_skip[i * 3 + 0];
        const float py = pos_skip[i * 3 + 1];
        const float pz = pos_skip[i * 3 + 2];

        double k0 = BIGKEY, k1 = BIGKEY, k2 = BIGKEY;
        for (int j = start + sub; j < end; j += 32) {
            const float4 q = pos4[j];
            const float dx = __fsub_rn(px, q.x);
            const float dy = __fsub_rn(py, q.y);
            const float dz = __fsub_rn(pz, q.z);
            const float dd = __fadd_rn(__fadd_rn(__fmul_rn(dx, dx), __fmul_rn(dy, dy)),
                                       __fmul_rn(dz, dz));
            const double kk = pkkey(dd, j);
            const double u0 = fmax(k0, kk); k0 = fmin(k0, kk);
            const double u1 = fmax(k1, u0); k1 = fmin(k1, u0);
            k2 = fmin(k2, u1);
        }
#pragma unroll
        for (int m = 1; m < 32; m <<= 1) {   // 5-step in-half butterfly
            const double o0 = __shfl_xor(k0, m);
            const double o1 = __shfl_xor(k1, m);
            const double o2 = __shfl_xor(k2, m);
            double u0 = fmax(k0, o0); k0 = fmin(k0, o0);
            double u1 = fmax(k1, u0); k1 = fmin(k1, u0);
            k2 = fmin(k2, u1);
            u1 = fmax(k1, o1); k1 = fmin(k1, o1);
            k2 = fmin(k2, u1);
            k2 = fmin(k2, o2);
        }
        const int i0 = __double2loint(k0);
        const int i1 = __double2loint(k1);
        const int i2 = __double2loint(k2);
        const float d0 = __int_as_float(__double2hiint(k0));
        const float d1 = __int_as_float(__double2hiint(k1));
        const float d2 = __int_as_float(__double2hiint(k2));
        const float w0r = 1.0f / fmaxf(d0, 1e-16f);
        const float w1r = 1.0f / fmaxf(d1, 1e-16f);
        const float w2r = 1.0f / fmaxf(d2, 1e-16f);
        const float inv = 1.0f / (w0r + w1r + w2r);
        const float w0 = w0r * inv, w1 = w1r * inv, w2 = w2r * inv;
        // gather: 8 cols per lane
        const float* xr0 = x + (size_t)i0 * CCH + sub * 8;
        const float* xr1 = x + (size_t)i1 * CCH + sub * 8;
        const float* xr2 = x + (size_t)i2 * CCH + sub * 8;
        const float4 a0 = *(const float4*)(xr0);
        const float4 a1 = *(const float4*)(xr0 + 4);
        const float4 c0 = *(const float4*)(xr1);
        const float4 c1 = *(const float4*)(xr1 + 4);
        const float4 e0 = *(const float4*)(xr2);
        const float4 e1 = *(const float4*)(xr2 + 4);
        const float y0 = w0 * a0.x + w1 * c0.x + w2 * e0.x;
        const float y1 = w0 * a0.y + w1 * c0.y + w2 * e0.y;
        const float y2 = w0 * a0.z + w1 * c0.z + w2 * e0.z;
        const float y3 = w0 * a0.w + w1 * c0.w + w2 * e0.w;
        const float y4 = w0 * a1.x + w1 * c1.x + w2 * e1.x;
        const float y5 = w0 * a1.y + w1 * c1.y + w2 * e1.y;
        const float y6 = w0 * a1.z + w1 * c1.z + w2 * e1.z;
        const float y7 = w0 * a1.w + w1 * c1.w + w2 * e1.w;
        uint4 pk;
        pk.x = (uint32_t)f2bf(y0) | ((uint32_t)f2bf(y1) << 16);
        pk.y = (uint32_t)f2bf(y2) | ((uint32_t)f2bf(y3) << 16);
        pk.z = (uint32_t)f2bf(y4) | ((uint32_t)f2bf(y5) << 16);
        pk.w = (uint32_t)f2bf(y6) | ((uint32_t)f2bf(y7) << 16);
        *(uint4*)(sA + rl * 392 + sub * 8) = pk;
    }
    __syncthreads();

    // ---------------- S2 ----------------
    if (wave >= 8) {
        // GEMM1 half1: ntiles 2(w-8),2(w-8)+1; A rows 16-31
        const u16* aA = sA + (16 + ml) * 392 + quad * 8;
        for (int kt = 0; kt < 12; ++kt) {
            short8 a1 = *(const short8*)(aA + kt * 32);
#pragma unroll
            for (int nt = 0; nt < 2; ++nt) {
                const int ntile = 2 * (wave - 8) + nt;
                short8 bfr = *(const short8*)(W1p + (size_t)((ntile * 12 + kt) * 64 + lane) * 8);
                acc[nt] = __builtin_amdgcn_mfma_f32_16x16x32_bf16(a1, bfr, acc[nt], 0, 0, 0);
            }
        }
    } else {
        // pack h rows 0-15 (bytes [0, 8448) -- disjoint from A rows 16-31)
#pragma unroll
        for (int nt = 0; nt < 2; ++nt) {
            const int n = (2 * wave + nt) * 16 + ml;
            const float bv = b1[n];
#pragma unroll
            for (int r = 0; r < 4; ++r) {
                const int m = quad * 4 + r;
                sA[m * 264 + n] = f2bf(fmaxf(acc[nt][r] + bv, 0.0f));
            }
        }
    }
    __syncthreads();

    // ---------------- S3 ----------------
    floatx4 acc2[2] = {};
    if (wave < 8) {
        // GEMM2 half0: h rows 0-15
        const u16* aH = sA + ml * 264 + quad * 8;
        for (int kt = 0; kt < 8; ++kt) {
            short8 a0 = *(const short8*)(aH + kt * 32);
#pragma unroll
            for (int nt = 0; nt < 2; ++nt) {
                const int ntile = 2 * wave + nt;
                short8 bfr = *(const short8*)(W2p + (size_t)((ntile * 8 + kt) * 64 + lane) * 8);
                acc2[nt] = __builtin_amdgcn_mfma_f32_16x16x32_bf16(a0, bfr, acc2[nt], 0, 0, 0);
            }
        }
    } else {
        // pack h rows 16-31 (bytes [8448, 16896) -- disjoint from h rows 0-15)
#pragma unroll
        for (int nt = 0; nt < 2; ++nt) {
            const int n = (2 * (wave - 8) + nt) * 16 + ml;
            const float bv = b1[n];
#pragma unroll
            for (int r = 0; r < 4; ++r) {
                const int m = 16 + quad * 4 + r;
                sA[m * 264 + n] = f2bf(fmaxf(acc[nt][r] + bv, 0.0f));
            }
        }
    }
    __syncthreads();

    // ---------------- S4 ----------------
    if (wave >= 8) {
        // GEMM2 half1 then pack own sOut rows 16-31
        const u16* aH = sA + (16 + ml) * 264 + quad * 8;
        for (int kt = 0; kt < 8; ++kt) {
            short8 a1 = *(const short8*)(aH + kt * 32);
#pragma unroll
            for (int nt = 0; nt < 2; ++nt) {
                const int ntile = 2 * (wave - 8) + nt;
                short8 bfr = *(const short8*)(W2p + (size_t)((ntile * 8 + kt) * 64 + lane) * 8);
                acc2[nt] = __builtin_amdgcn_mfma_f32_16x16x32_bf16(a1, bfr, acc2[nt], 0, 0, 0);
            }
        }
#pragma unroll
        for (int nt = 0; nt < 2; ++nt) {
            const int n = (2 * (wave - 8) + nt) * 16 + ml;
            const float bv = b2[n];
#pragma unroll
            for (int r = 0; r < 4; ++r) {
                const int m = 16 + quad * 4 + r;
                sOut[m * 256 + n] = fmaxf(acc2[nt][r] + bv, 0.0f);
            }
        }
    } else {
        // pack sOut rows 0-15
#pragma unroll
        for (int nt = 0; nt < 2; ++nt) {
            const int n = (2 * wave + nt) * 16 + ml;
            const float bv = b2[n];
#pragma unroll
            for (int r = 0; r < 4; ++r) {
                const int m = quad * 4 + r;
                sOut[m * 256 + n] = fmaxf(acc2[nt][r] + bv, 0.0f);
            }
        }
    }
    __syncthreads();

    // ---------------- S5: store + tail ----------------
    {
        float* dst = out + (size_t)row0 * HDIM;
#pragma unroll
        for (int k = 0; k < 2; ++k) {
            const int e = t + 1024 * k;
            *(float4*)(dst + e * 4) = *(const float4*)(sOut + e * 4);
        }
    }
    if (t < 128) {
        const int e = blockIdx.x * 128 + t;
        const size_t base = (size_t)NSKIP * HDIM;
        if (e < NSKIP * 3) out[base + e] = pos_skip[e];
        else               out[base + e] = (float)batch_skip[e - NSKIP * 3];
    }
}

extern "C" void kernel_launch(void* const* d_in, const int* in_sizes, int n_in,
                              void* d_out, int out_size, void* d_ws, size_t ws_size,
                              hipStream_t stream) {
    const float* x         = (const float*)d_in[0];
    const float* pos       = (const float*)d_in[1];
    const int*   batch     = (const int*)d_in[2];
    const float* x_skip    = (const float*)d_in[3];
    const float* pos_skip  = (const float*)d_in[4];
    const int*   batch_skip= (const int*)d_in[5];
    const float* W1        = (const float*)d_in[6];
    const float* b1        = (const float*)d_in[7];
    const float* W2        = (const float*)d_in[8];
    const float* b2        = (const float*)d_in[9];
    float* out = (float*)d_out;

    // ws layout:
    char* ws = (char*)d_ws;
    u16*    W1p   = (u16*)ws;                      // 196608 B
    u16*    W2p   = (u16*)(ws + 196608);           // 131072 B
    int*    range = (int*)(ws + 327680);           // 32 B
    float4* pos4  = (float4*)(ws + 327712);        // 65536 B

    prep_kernel<<<80, 256, 0, stream>>>(W1, W2, W1p, W2p, pos, pos4, batch, range);
    mega_kernel<<<NSKIP / 32, 1024, 0, stream>>>(x, x_skip, pos4, range,
                                                 W1p, b1, W2p, b2,
                                                 pos_skip, batch_skip, out);
}

// Round 15
// 109.252 us; speedup vs baseline: 1.0581x; 1.0581x over previous
//
#include <hip/hip_runtime.h>
#include <stdint.h>

#define NPTS   4096
#define NSKIP  16384
#define CCH    256
#define CSK    128
#define DIN    384
#define HDIM   256
#define BIGF   1e10f

typedef unsigned short u16;
typedef __attribute__((ext_vector_type(8))) short short8;
typedef __attribute__((ext_vector_type(4))) float floatx4;

__device__ __forceinline__ u16 f2bf(float f) {
    union { float f; uint32_t u; } c; c.f = f;
    uint32_t u = c.u;
    return (u16)((u + 0x7FFFu + ((u >> 16) & 1u)) >> 16);
}

// Pack (non-negative fp32 dist, idx) into a positive double whose numeric
// order == (dist, idx) lexicographic order (exact top_k tie semantics).
__device__ __forceinline__ double pkkey(float d, int j) {
    return __hiloint2double(__float_as_int(d), j);
}

// ---------------------------------------------------------------------------
// k1 (R21 = R12 revert): prep — 80 blocks. Blocks 0-47 pack W1, 48-79 pack
// W2 (ntile-major MFMA B-fragment layout); blocks 48-63 also build pos4.
// ---------------------------------------------------------------------------
__global__ __launch_bounds__(256) void prep_kernel(
    const float* __restrict__ W1, const float* __restrict__ W2,
    u16* __restrict__ W1p, u16* __restrict__ W2p,
    const float* __restrict__ pos, float4* __restrict__ pos4)
{
    const int bid = blockIdx.x;
    const int t = threadIdx.x;

    const float* W = (bid < 48) ? W1 : W2;
    u16* Wp       = (bid < 48) ? W1p : W2p;
    const int KT  = (bid < 48) ? 12 : 8;
    const int g   = ((bid < 48) ? bid : (bid - 48)) * 256 + t;

    const int lane = g & 63;
    const int kt = (g >> 6) % KT;
    const int nt = (g >> 6) / KT;
    const int kbase = kt * 32 + (lane >> 4) * 8;
    const int n = nt * 16 + (lane & 15);
    u16 v[8];
#pragma unroll
    for (int j = 0; j < 8; ++j) v[j] = f2bf(W[(size_t)(kbase + j) * HDIM + n]);
#pragma unroll
    for (int j = 0; j < 8; ++j) Wp[(size_t)g * 8 + j] = v[j];

    if (bid >= 48 && bid < 64) {
        const int p = (bid - 48) * 256 + t;
        pos4[p] = make_float4(pos[p * 3 + 0], pos[p * 3 + 1], pos[p * 3 + 2], 0.0f);
    }
}

// ---------------------------------------------------------------------------
// k2 (R21 = R12 revert): mega kernel — 32 rows/block, 512 blocks (exactly
// co-residency capacity), 1024 threads (16 waves), VGPR<=64.
//   A: KNN (32 thr/pt) -> LDS idx/w.  B: interp gather + pack -> sA.
//   C: GEMM1 -> h relu pack -> GEMM2 -> coalesced epilogue + tail.
// Best-measured configuration: 108.2 us (R12), re-verified here.
// ---------------------------------------------------------------------------
__global__ __launch_bounds__(1024, 8) void mega_kernel(
    const float* __restrict__ x, const float* __restrict__ x_skip,
    const float4* __restrict__ pos4, const int* __restrict__ batch,
    const u16* __restrict__ W1p, const float* __restrict__ b1,
    const u16* __restrict__ W2p, const float* __restrict__ b2,
    const float* __restrict__ pos_skip, const int* __restrict__ batch_skip,
    float* __restrict__ out)
{
    __shared__ u16 sA[32 * 392];     // 25088 B; reused as h[32][264]
    __shared__ float sOut[32 * 256]; // 32768 B f32 epilogue staging
    __shared__ int   sIdx[32 * 3];
    __shared__ float sWgt[32 * 3];
    __shared__ int   sRange[5];
    const int t = threadIdx.x;
    const int row0 = blockIdx.x * 32;
    const int wave = t >> 6, lane = t & 63;
    const int quad = lane >> 4, ml = lane & 15;

    // --- batch range table (binary search; L1-resident batch array) ---
    if (t < 5) {
        int lo = 0, hi = NPTS;
        while (lo < hi) {
            const int m = (lo + hi) >> 1;
            if (batch[m] < t) lo = m + 1; else hi = m;
        }
        sRange[t] = lo;
    }
    // --- skip copy first (independent): loads issue under the knn scan ---
    {
        const int row = t >> 5, c4 = t & 31;
        const float4 v = *(const float4*)(x_skip + (size_t)(row0 + row) * CSK + c4 * 4);
        uint2 pk;
        pk.x = (uint32_t)f2bf(v.x) | ((uint32_t)f2bf(v.y) << 16);
        pk.y = (uint32_t)f2bf(v.z) | ((uint32_t)f2bf(v.w) << 16);
        *(uint2*)(sA + row * 392 + CCH + c4 * 4) = pk;
    }
    __syncthreads();

    // --- Phase A: KNN (32 threads/pt, stride-32 scan, f64-key top-3) ---
    {
        const int rl = t >> 5;          // 0..31
        const int sub = t & 31;
        const int i = row0 + rl;
        const int b = batch_skip[i];
        const int start = sRange[b], end = sRange[b + 1];

        const float px = pos_skip[i * 3 + 0];
        const float py = pos_skip[i * 3 + 1];
        const float pz = pos_skip[i * 3 + 2];

        const double BIGKEY = pkkey(BIGF, 0x7FFFFFFF);
        double k0 = BIGKEY, k1 = BIGKEY, k2 = BIGKEY;

        for (int j = start + sub; j < end; j += 32) {
            const float4 q = pos4[j];
            const float dx = __fsub_rn(px, q.x);
            const float dy = __fsub_rn(py, q.y);
            const float dz = __fsub_rn(pz, q.z);
            const float dd = __fadd_rn(__fadd_rn(__fmul_rn(dx, dx), __fmul_rn(dy, dy)),
                                       __fmul_rn(dz, dz));
            const double kk = pkkey(dd, j);
            const double u0 = fmax(k0, kk); k0 = fmin(k0, kk);
            const double u1 = fmax(k1, u0); k1 = fmin(k1, u0);
            k2 = fmin(k2, u1);
        }

#pragma unroll
        for (int m = 1; m < 32; m <<= 1) {
            const double o0 = __shfl_xor(k0, m);
            const double o1 = __shfl_xor(k1, m);
            const double o2 = __shfl_xor(k2, m);
            double u0 = fmax(k0, o0); k0 = fmin(k0, o0);
            double u1 = fmax(k1, u0); k1 = fmin(k1, u0);
            k2 = fmin(k2, u1);
            u1 = fmax(k1, o1); k1 = fmin(k1, o1);
            k2 = fmin(k2, u1);
            k2 = fmin(k2, o2);
        }

        if (sub == 0) {
            const float d0 = __int_as_float(__double2hiint(k0));
            const float d1 = __int_as_float(__double2hiint(k1));
            const float d2 = __int_as_float(__double2hiint(k2));
            const float w0 = 1.0f / fmaxf(d0, 1e-16f);
            const float w1 = 1.0f / fmaxf(d1, 1e-16f);
            const float w2 = 1.0f / fmaxf(d2, 1e-16f);
            const float inv = 1.0f / (w0 + w1 + w2);
            sIdx[rl * 3 + 0] = __double2loint(k0);
            sIdx[rl * 3 + 1] = __double2loint(k1);
            sIdx[rl * 3 + 2] = __double2loint(k2);
            sWgt[rl * 3 + 0] = w0 * inv;
            sWgt[rl * 3 + 1] = w1 * inv;
            sWgt[rl * 3 + 2] = w2 * inv;
        }
    }
    __syncthreads();

    // --- Phase B: interp gather, 2 slots/thread ---
#pragma unroll
    for (int k = 0; k < 2; ++k) {
        const int g = t + 1024 * k;
        const int row = g >> 6, c4 = g & 63;
        const int i0 = sIdx[row * 3 + 0], i1 = sIdx[row * 3 + 1], i2 = sIdx[row * 3 + 2];
        const float w0 = sWgt[row * 3 + 0], w1 = sWgt[row * 3 + 1], w2 = sWgt[row * 3 + 2];
        const float4 v0 = *(const float4*)(x + (size_t)i0 * CCH + c4 * 4);
        const float4 v1 = *(const float4*)(x + (size_t)i1 * CCH + c4 * 4);
        const float4 v2 = *(const float4*)(x + (size_t)i2 * CCH + c4 * 4);
        const float a  = w0 * v0.x + w1 * v1.x + w2 * v2.x;
        const float bq = w0 * v0.y + w1 * v1.y + w2 * v2.y;
        const float cq = w0 * v0.z + w1 * v1.z + w2 * v2.z;
        const float dq = w0 * v0.w + w1 * v1.w + w2 * v2.w;
        uint2 pk;
        pk.x = (uint32_t)f2bf(a)  | ((uint32_t)f2bf(bq) << 16);
        pk.y = (uint32_t)f2bf(cq) | ((uint32_t)f2bf(dq) << 16);
        *(uint2*)(sA + row * 392 + c4 * 4) = pk;
    }
    __syncthreads();

    // --- Phase C1: GEMM1 A[32x384] @ W1 -> h[32x256]; 1 ntile/wave ---
    floatx4 acc[2] = {};
    {
        const u16* aA = sA + ml * 392 + quad * 8;
        for (int kt = 0; kt < 12; ++kt) {
            short8 a0 = *(const short8*)(aA + kt * 32);
            short8 a1 = *(const short8*)(aA + 16 * 392 + kt * 32);
            short8 bfr = *(const short8*)(W1p + (size_t)((wave * 12 + kt) * 64 + lane) * 8);
            acc[0] = __builtin_amdgcn_mfma_f32_16x16x32_bf16(a0, bfr, acc[0], 0, 0, 0);
            acc[1] = __builtin_amdgcn_mfma_f32_16x16x32_bf16(a1, bfr, acc[1], 0, 0, 0);
        }
    }
    __syncthreads();

    // --- h = relu(acc + b1) -> LDS bf16 [32 x 264] ---
    {
        const int n = wave * 16 + ml;
        const float bv = b1[n];
#pragma unroll
        for (int mt = 0; mt < 2; ++mt) {
#pragma unroll
            for (int r = 0; r < 4; ++r) {
                const int m = mt * 16 + quad * 4 + r;
                sA[m * 264 + n] = f2bf(fmaxf(acc[mt][r] + bv, 0.0f));
            }
        }
    }
    __syncthreads();

    // --- Phase C2: GEMM2 h[32x256] @ W2; 1 ntile/wave ---
    floatx4 acc2[2] = {};
    {
        const u16* aH = sA + ml * 264 + quad * 8;
        for (int kt = 0; kt < 8; ++kt) {
            short8 a0 = *(const short8*)(aH + kt * 32);
            short8 a1 = *(const short8*)(aH + 16 * 264 + kt * 32);
            short8 bfr = *(const short8*)(W2p + (size_t)((wave * 8 + kt) * 64 + lane) * 8);
            acc2[0] = __builtin_amdgcn_mfma_f32_16x16x32_bf16(a0, bfr, acc2[0], 0, 0, 0);
            acc2[1] = __builtin_amdgcn_mfma_f32_16x16x32_bf16(a1, bfr, acc2[1], 0, 0, 0);
        }
    }

    // --- epilogue: fragments -> sOut (f32) -> coalesced contiguous stores ---
    {
        const int n = wave * 16 + ml;
        const float bv = b2[n];
#pragma unroll
        for (int mt = 0; mt < 2; ++mt) {
#pragma unroll
            for (int r = 0; r < 4; ++r) {
                const int m = mt * 16 + quad * 4 + r;
                sOut[m * 256 + n] = fmaxf(acc2[mt][r] + bv, 0.0f);
            }
        }
    }
    __syncthreads();
    {
        float* dst = out + (size_t)row0 * HDIM;
#pragma unroll
        for (int k = 0; k < 2; ++k) {
            const int e = t + 1024 * k;
            *(float4*)(dst + e * 4) = *(const float4*)(sOut + e * 4);
        }
    }

    // --- tail: 128 flat elems per block ---
    if (t < 128) {
        const int e = blockIdx.x * 128 + t;
        const size_t base = (size_t)NSKIP * HDIM;
        if (e < NSKIP * 3) out[base + e] = pos_skip[e];
        else               out[base + e] = (float)batch_skip[e - NSKIP * 3];
    }
}

extern "C" void kernel_launch(void* const* d_in, const int* in_sizes, int n_in,
                              void* d_out, int out_size, void* d_ws, size_t ws_size,
                              hipStream_t stream) {
    const float* x         = (const float*)d_in[0];
    const float* pos       = (const float*)d_in[1];
    const int*   batch     = (const int*)d_in[2];
    const float* x_skip    = (const float*)d_in[3];
    const float* pos_skip  = (const float*)d_in[4];
    const int*   batch_skip= (const int*)d_in[5];
    const float* W1        = (const float*)d_in[6];
    const float* b1        = (const float*)d_in[7];
    const float* W2        = (const float*)d_in[8];
    const float* b2        = (const float*)d_in[9];
    float* out = (float*)d_out;

    // ws layout:
    char* ws = (char*)d_ws;
    u16*    W1p   = (u16*)ws;                      // 196608 B
    u16*    W2p   = (u16*)(ws + 196608);           // 131072 B
    float4* pos4  = (float4*)(ws + 327680);        // 65536 B

    prep_kernel<<<80, 256, 0, stream>>>(W1, W2, W1p, W2p, pos, pos4);
    mega_kernel<<<NSKIP / 32, 1024, 0, stream>>>(x, x_skip, pos4, batch,
                                                 W1p, b1, W2p, b2,
                                                 pos_skip, batch_skip, out);
}